// Round 6
// baseline (1257.280 us; speedup 1.0000x reference)
//
#include <hip/hip_runtime.h>

typedef __attribute__((ext_vector_type(8))) short bf16x8;
typedef __attribute__((ext_vector_type(4))) float f32x4;

#define NBLK  512
#define NTHR  1024    // 16 waves, 1 block/CU (128 KB LDS)
#define NT    4       // 16-row tiles per wave:  512*16*4*16 = 524288 rows
#define DOUT  128

__device__ __forceinline__ unsigned short bf_rne(float x) {
  unsigned u = __builtin_bit_cast(unsigned, x);
  return (unsigned short)((u + 0x7FFFu + ((u >> 16) & 1u)) >> 16);
}

// fp32 -> bf16 hi (truncate) + bf16 lo (RNE of residual); x ~ hi+lo to ~2^-15 rel
__device__ __forceinline__ void split2(float x, short& hi, short& lo) {
  unsigned u = __builtin_bit_cast(unsigned, x);
  float hf = __builtin_bit_cast(float, u & 0xFFFF0000u);
  hi = (short)(unsigned short)(u >> 16);
  lo = (short)bf_rne(x - hf);
}

// Autonomous-wave design: weights live in LDS (staged once), x streams through
// registers. NO barriers in the main loop -> no vmcnt drains, every wave keeps
// loads in flight continuously (R1-R5 were stuck at ~40% load duty cycle
// behind barrier-locked staging).
// LDS layout: for cix = ct*8+ks (ct=col-tile 0..7, ks=k-step 0..7), lane l:
//   hi bf16x8 at short-index cix*1024 + l*8   (byte: cix*2048 + l*16)
//   lo bf16x8 at short-index cix*1024 + 512 + l*8
// Lane l's B-frag = W[col = ct*16 + (l&15)][k = ks*32 + (l>>4)*8 + j], masked.
// Each wave-read spans 1 KB contiguous -> conflict-free (2 lanes/bank = free).
__global__ __launch_bounds__(NTHR, 4)   // 4 waves/EU -> VGPR cap 128 (est ~100)
void dagmm(const float* __restrict__ x0, const float* __restrict__ x1,
           const float* __restrict__ w0, const float* __restrict__ w1,
           const float* __restrict__ m0, const float* __restrict__ m1,
           float* __restrict__ out)
{
  __shared__ short wl[65536];   // 128 KB masked+split weights

  const int t   = threadIdx.x;
  const int l   = t & 63;
  const int w   = t >> 6;       // wave 0..15
  const int l16 = l & 15;
  const int lq  = l >> 4;

  // ---------- stage masked, hi/lo-split weights into LDS (once) ----------
#pragma unroll
  for (int rep = 0; rep < 4; ++rep) {
    const int chunk = rep * 1024 + t;          // 4096 chunks = 64 cix * 64 lanes
    const int cl  = chunk & 63;
    const int cks = (chunk >> 6) & 7;
    const int cct = (chunk >> 9) & 7;
    const int col = cct * 16 + (cl & 15);
    const int k0  = cks * 32 + ((cl >> 4) << 3);   // 0..248, never straddles 128
    const float* wp = (k0 < 128) ? (w0 + col * 128 + k0) : (w1 + col * 128 + (k0 - 128));
    const float* mp = (k0 < 128) ? (m0 + col * 128 + k0) : (m1 + col * 128 + (k0 - 128));
    float4 wa = *(const float4*)wp, wb = *(const float4*)(wp + 4);
    float4 ma = *(const float4*)mp, mb = *(const float4*)(mp + 4);
    float v[8] = {wa.x*ma.x, wa.y*ma.y, wa.z*ma.z, wa.w*ma.w,
                  wb.x*mb.x, wb.y*mb.y, wb.z*mb.z, wb.w*mb.w};
    bf16x8 hv, lv;
#pragma unroll
    for (int j = 0; j < 8; ++j) { short h, lo2; split2(v[j], h, lo2); hv[j] = h; lv[j] = lo2; }
    const int base = (cct * 8 + cks) * 1024 + cl * 8;
    *(bf16x8*)&wl[base]       = hv;
    *(bf16x8*)&wl[base + 512] = lv;
  }
  __syncthreads();   // only barrier in the kernel

  const int gw = blockIdx.x * 16 + w;   // global wave id; owns rows [gw*64, gw*64+64)

  // x address for (tile gt, k-step gk): lane reads 8 consecutive floats
  auto xptr = [&](int gt, int gk) -> const float* {
    const float* bp = (gk < 4) ? x0 : x1;
    return bp + (size_t)(gw * 64 + gt * 16 + l16) * 128 + (gk & 3) * 32 + lq * 8;
  };

  // depth-2 register prefetch (statically indexed by ks&1 after unroll)
  float4 pf[2][2];
  {
    const float* p0 = xptr(0, 0);
    pf[0][0] = *(const float4*)p0; pf[0][1] = *(const float4*)(p0 + 4);
    const float* p1 = xptr(0, 1);
    pf[1][0] = *(const float4*)p1; pf[1][1] = *(const float4*)(p1 + 4);
  }

  for (int tt = 0; tt < NT; ++tt) {
    f32x4 acc[8];
#pragma unroll
    for (int ct = 0; ct < 8; ++ct) acc[ct] = (f32x4){0.f, 0.f, 0.f, 0.f};

#pragma unroll
    for (int ks = 0; ks < 8; ++ks) {
      // consume slot (waits only on these 2 loads), then immediately refill
      float4 c0 = pf[ks & 1][0], c1 = pf[ks & 1][1];
      int nt2 = tt, nk2 = ks + 2;
      if (nk2 >= 8) { nk2 -= 8; ++nt2; }
      if (nt2 >= NT) { nt2 = tt; nk2 = ks; }   // tail: harmless re-read in range
      const float* np = xptr(nt2, nk2);
      pf[ks & 1][0] = *(const float4*)np;
      pf[ks & 1][1] = *(const float4*)(np + 4);

      float vv[8] = {c0.x, c0.y, c0.z, c0.w, c1.x, c1.y, c1.z, c1.w};
      bf16x8 ah, al;
#pragma unroll
      for (int j = 0; j < 8; ++j) { short h, lo2; split2(vv[j], h, lo2); ah[j] = h; al[j] = lo2; }

#pragma unroll
      for (int ct = 0; ct < 8; ++ct) {
        const int bi = (ct * 8 + ks) * 1024 + l * 8;
        bf16x8 bh = *(const bf16x8*)&wl[bi];
        bf16x8 bl = *(const bf16x8*)&wl[bi + 512];
        acc[ct] = __builtin_amdgcn_mfma_f32_16x16x32_bf16(ah, bh, acc[ct], 0, 0, 0);
        acc[ct] = __builtin_amdgcn_mfma_f32_16x16x32_bf16(ah, bl, acc[ct], 0, 0, 0);
        acc[ct] = __builtin_amdgcn_mfma_f32_16x16x32_bf16(al, bh, acc[ct], 0, 0, 0);
      }
    }

    // C/D layout: col = l16, row = lq*4 + r (m89-verified, matches R1-R5 pass)
    const size_t r0 = (size_t)gw * 64 + tt * 16 + lq * 4;
#pragma unroll
    for (int ct = 0; ct < 8; ++ct)
#pragma unroll
      for (int r = 0; r < 4; ++r)
        out[(r0 + r) * DOUT + ct * 16 + l16] = acc[ct][r];
  }
}

extern "C" void kernel_launch(void* const* d_in, const int* in_sizes, int n_in,
                              void* d_out, int out_size, void* d_ws, size_t ws_size,
                              hipStream_t stream) {
  const float* x0 = (const float*)d_in[0];
  const float* x1 = (const float*)d_in[1];
  const float* w0 = (const float*)d_in[2];
  const float* w1 = (const float*)d_in[3];
  const float* m0 = (const float*)d_in[4];
  const float* m1 = (const float*)d_in[5];
  dagmm<<<NBLK, NTHR, 0, stream>>>(x0, x1, w0, w1, m0, m1, (float*)d_out);
}